// Round 2
// baseline (2714.825 us; speedup 1.0000x reference)
//
#include <hip/hip_runtime.h>

typedef __attribute__((ext_vector_type(8))) short short8;
typedef _Float16 half8 __attribute__((ext_vector_type(8)));
typedef __attribute__((ext_vector_type(4))) float f32x4;
typedef __attribute__((ext_vector_type(4))) unsigned int uint4v;

#define B_   8
#define LX_  2048
#define LY_  2048
#define D_   256

__device__ __forceinline__ unsigned short f2bf(float f) {
  unsigned u = __builtin_bit_cast(unsigned, f);
  u += 0x7FFF + ((u >> 16) & 1);          // RNE truncate (inputs are finite)
  return (unsigned short)(u >> 16);
}
__device__ __forceinline__ float bf2f(unsigned short h) {
  unsigned u = ((unsigned)h) << 16;
  return __builtin_bit_cast(float, u);
}

// ---------------- W -> hi/lo bf16 split (65536 elems) ----------------
__global__ __launch_bounds__(256) void wsplit_kernel(
    const float* __restrict__ W, unsigned short* __restrict__ Whi,
    unsigned short* __restrict__ Wlo) {
  int i = blockIdx.x * 256 + threadIdx.x;
  float w = W[i];
  unsigned short hi = f2bf(w);
  Whi[i] = hi;
  Wlo[i] = f2bf(w - bf2f(hi));
}

// ---------------- proj = relu(X @ W^T + b), accurate via hi/lo split --
// X: [M=16384][256] fp32 ; out fp16 [M][256]. 64 rows/block, 4 waves.
__global__ __launch_bounds__(256) void proj_kernel(
    const float* __restrict__ X, const float* __restrict__ bias,
    const unsigned short* __restrict__ Whi, const unsigned short* __restrict__ Wlo,
    _Float16* __restrict__ out) {
  int lane = threadIdx.x & 63, wave = threadIdx.x >> 6;
  int q = lane >> 4, n15 = lane & 15;
  int row0 = blockIdx.x * 64 + wave * 16;

  // A fragments: A[m=lane&15][k=q*8+j], hi+lo split (bf16)
  short8 ahi[8], alo[8];
  const float* xrow = X + (size_t)(row0 + n15) * D_;
  for (int kk = 0; kk < 8; ++kk) {
    const float* p = xrow + kk * 32 + q * 8;
    f32x4 f0 = *(const f32x4*)(p);
    f32x4 f1 = *(const f32x4*)(p + 4);
    float v[8] = {f0[0], f0[1], f0[2], f0[3], f1[0], f1[1], f1[2], f1[3]};
    for (int j = 0; j < 8; ++j) {
      unsigned short h = f2bf(v[j]);
      ahi[kk][j] = (short)h;
      alo[kk][j] = (short)f2bf(v[j] - bf2f(h));
    }
  }

  for (int et = 0; et < 16; ++et) {
    int e = et * 16 + n15;
    const unsigned short* whp = Whi + (size_t)e * D_ + q * 8;
    const unsigned short* wlp = Wlo + (size_t)e * D_ + q * 8;
    f32x4 acc = {0.f, 0.f, 0.f, 0.f};
    for (int kk = 0; kk < 8; ++kk) {
      short8 bh = *(const short8*)(whp + kk * 32);
      short8 bl = *(const short8*)(wlp + kk * 32);
      acc = __builtin_amdgcn_mfma_f32_16x16x32_bf16(ahi[kk], bh, acc, 0, 0, 0);
      acc = __builtin_amdgcn_mfma_f32_16x16x32_bf16(alo[kk], bh, acc, 0, 0, 0);
      acc = __builtin_amdgcn_mfma_f32_16x16x32_bf16(ahi[kk], bl, acc, 0, 0, 0);
    }
    float bv = bias[e];
    for (int r = 0; r < 4; ++r) {
      float v = acc[r] + bv;
      v = v > 0.f ? v : 0.f;
      out[(size_t)(row0 + q * 4 + r) * D_ + e] = (_Float16)v;
    }
  }
}

// ---------------- y fp32 [B][LY][D] -> yT fp16 [B][D][LY] -------------
__global__ __launch_bounds__(256) void transpose_kernel(
    const float* __restrict__ Y, _Float16* __restrict__ YT) {
  __shared__ _Float16 tile[64][72];  // +8 pad, rows 16B-aligned
  int id = blockIdx.x;
  int db = id & 3, nb = (id >> 2) & 31, b = id >> 7;
  int t = threadIdx.x;
  int nl = t >> 2, ds = t & 3;
  const float* src = Y + (size_t)(b * LY_ + nb * 64 + nl) * D_ + db * 64 + ds * 16;
  for (int i = 0; i < 4; ++i) {
    f32x4 f = *(const f32x4*)(src + i * 4);
    for (int j = 0; j < 4; ++j) tile[ds * 16 + i * 4 + j][nl] = (_Float16)f[j];
  }
  __syncthreads();
  int dl = t >> 2, nsub = t & 3;
  uint4v v0 = *(const uint4v*)&tile[dl][nsub * 16];
  uint4v v1 = *(const uint4v*)&tile[dl][nsub * 16 + 8];
  _Float16* dst = YT + (size_t)(b * D_ + db * 64 + dl) * LY_ + nb * 64 + nsub * 16;
  *(uint4v*)(dst) = v0;
  *(uint4v*)(dst + 8) = v1;
}

// ---------------- flash attention over y tiles ------------------------
// grid 256: (b, 64 x-rows). 4 waves x 16 rows. y tiles of 32.
__global__ __launch_bounds__(256) void flash_kernel(
    const _Float16* __restrict__ XP, const _Float16* __restrict__ YP,
    const _Float16* __restrict__ YT, const int* __restrict__ MASK,
    float* __restrict__ OUT) {
  __shared__ _Float16 yp_t[32][264];   // [n][d], +8 pad (row = 528 B, 16B-aligned)
  __shared__ _Float16 yT_t[256][40];   // [d][n], +8 pad (row = 80 B)
  __shared__ _Float16 pbuf[4][16][40]; // per-wave P round-trip
  __shared__ int msk[32];

  int t = threadIdx.x;
  int lane = t & 63, wave = t >> 6;
  int q = lane >> 4, n15 = lane & 15;
  int b = blockIdx.x >> 5, xb = blockIdx.x & 31;
  int row0 = xb * 64 + wave * 16;

  // x_proj A-fragments for this wave's 16 rows (kept in regs all loop)
  half8 a[8];
  const _Float16* xrow = XP + (size_t)(b * LX_ + row0 + n15) * D_ + q * 8;
  for (int kk = 0; kk < 8; ++kk) a[kk] = *(const half8*)(xrow + kk * 32);

  float m_r[4], l_r[4];
  for (int r = 0; r < 4; ++r) { m_r[r] = -1e30f; l_r[r] = 0.f; }
  f32x4 oacc[16];
  for (int dt = 0; dt < 16; ++dt) oacc[dt] = (f32x4){0.f, 0.f, 0.f, 0.f};

  const _Float16* ypb = YP + (size_t)b * LY_ * D_;
  const _Float16* yTb = YT + (size_t)b * D_ * LY_;
  const int* mb = MASK + b * LY_;

  for (int y0 = 0; y0 < LY_; y0 += 32) {
    __syncthreads();  // previous iteration's consumers done
    // stage y_proj tile [32][256] fp16 : 1024 16B chunks
    for (int i = 0; i < 4; ++i) {
      int c = t + i * 256;
      int n = c >> 5, dc = c & 31;
      uint4v v = *(const uint4v*)(ypb + (size_t)(y0 + n) * D_ + dc * 8);
      *(uint4v*)&yp_t[n][dc * 8] = v;
    }
    // stage yT tile [256][32] fp16 : 1024 16B chunks
    for (int i = 0; i < 4; ++i) {
      int c = t + i * 256;
      int d = c >> 2, nc = c & 3;
      uint4v v = *(const uint4v*)(yTb + (size_t)d * LY_ + y0 + nc * 8);
      *(uint4v*)&yT_t[d][nc * 8] = v;
    }
    if (t < 32) msk[t] = mb[y0 + t];
    __syncthreads();

    // ---- QK^T : S[16m x 32n], two 16-col MFMA chains
    f32x4 S0 = {0.f, 0.f, 0.f, 0.f}, S1 = {0.f, 0.f, 0.f, 0.f};
    for (int kk = 0; kk < 8; ++kk) {
      half8 b0 = *(const half8*)&yp_t[n15][kk * 32 + q * 8];
      S0 = __builtin_amdgcn_mfma_f32_16x16x32_f16(a[kk], b0, S0, 0, 0, 0);
    }
    for (int kk = 0; kk < 8; ++kk) {
      half8 b1 = *(const half8*)&yp_t[16 + n15][kk * 32 + q * 8];
      S1 = __builtin_amdgcn_mfma_f32_16x16x32_f16(a[kk], b1, S1, 0, 0, 0);
    }
    int mk0 = msk[n15], mk1 = msk[16 + n15];
    float s0[4], s1[4];
    for (int r = 0; r < 4; ++r) {
      s0[r] = mk0 ? -1e30f : S0[r];
      s1[r] = mk1 ? -1e30f : S1[r];
    }
    // ---- online softmax (rows = q*4+r live in 16-lane quad groups)
    float al[4];
    _Float16 ph0[4], ph1[4];
    bool allone = true;
    for (int r = 0; r < 4; ++r) {
      float tm = fmaxf(s0[r], s1[r]);
      tm = fmaxf(tm, __shfl_xor(tm, 1));
      tm = fmaxf(tm, __shfl_xor(tm, 2));
      tm = fmaxf(tm, __shfl_xor(tm, 4));
      tm = fmaxf(tm, __shfl_xor(tm, 8));
      float mn = fmaxf(m_r[r], tm);
      al[r] = __expf(m_r[r] - mn);
      m_r[r] = mn;
      // round p to fp16 FIRST, then use the rounded value for both l and PV
      ph0[r] = (_Float16)__expf(s0[r] - mn);
      ph1[r] = (_Float16)__expf(s1[r] - mn);
      float rsv = (float)ph0[r] + (float)ph1[r];
      rsv += __shfl_xor(rsv, 1);
      rsv += __shfl_xor(rsv, 2);
      rsv += __shfl_xor(rsv, 4);
      rsv += __shfl_xor(rsv, 8);
      l_r[r] = l_r[r] * al[r] + rsv;
      allone = allone && (al[r] == 1.0f);
    }
    if (__ballot(!allone)) {  // wave-uniform skip when max unchanged
      for (int dt = 0; dt < 16; ++dt)
        for (int r = 0; r < 4; ++r) oacc[dt][r] *= al[r];
    }
    // ---- P: C-layout -> LDS -> A-layout (wave-local, in-order DS pipe)
    for (int r = 0; r < 4; ++r) {
      pbuf[wave][q * 4 + r][n15] = ph0[r];
      pbuf[wave][q * 4 + r][16 + n15] = ph1[r];
    }
    half8 pa = *(const half8*)&pbuf[wave][n15][q * 8];
    // ---- PV: O[16m x 256d] += P[16x32] @ y[32x256]
    for (int dt = 0; dt < 16; ++dt) {
      half8 bb = *(const half8*)&yT_t[dt * 16 + n15][q * 8];
      oacc[dt] = __builtin_amdgcn_mfma_f32_16x16x32_f16(pa, bb, oacc[dt], 0, 0, 0);
    }
  }

  // epilogue: O / l
  float inv[4];
  for (int r = 0; r < 4; ++r) inv[r] = 1.0f / l_r[r];
  float* ob = OUT + (size_t)(b * LX_ + row0) * D_;
  for (int dt = 0; dt < 16; ++dt)
    for (int r = 0; r < 4; ++r)
      ob[(size_t)(q * 4 + r) * D_ + dt * 16 + n15] = oacc[dt][r] * inv[r];
}

extern "C" void kernel_launch(void* const* d_in, const int* in_sizes, int n_in,
                              void* d_out, int out_size, void* d_ws, size_t ws_size,
                              hipStream_t stream) {
  const float* x     = (const float*)d_in[0];  // [8,2048,256]
  const float* y     = (const float*)d_in[1];  // [8,2048,256]
  const int*   ymask = (const int*)  d_in[2];  // [8,2048]
  const float* W     = (const float*)d_in[3];  // [256,256]
  const float* bias  = (const float*)d_in[4];  // [256]
  float* out = (float*)d_out;

  // ws layout (~24.5 MB total)
  char* ws = (char*)d_ws;
  unsigned short* Whi = (unsigned short*)(ws);                    // 128 KB
  unsigned short* Wlo = (unsigned short*)(ws + (131072));         // 128 KB
  _Float16* XP  = (_Float16*)(ws + (262144));                     // 8 MB
  _Float16* YP  = (_Float16*)(ws + (262144 + 8388608));           // 8 MB
  _Float16* YT  = (_Float16*)(ws + (262144 + 2 * 8388608));       // 8 MB

  wsplit_kernel<<<256, 256, 0, stream>>>(W, Whi, Wlo);
  proj_kernel<<<256, 256, 0, stream>>>(x, bias, Whi, Wlo, XP);    // 16384 rows
  proj_kernel<<<256, 256, 0, stream>>>(y, bias, Whi, Wlo, YP);
  transpose_kernel<<<1024, 256, 0, stream>>>(y, YT);
  flash_kernel<<<256, 256, 0, stream>>>(XP, YP, YT, ymask, out);
}

// Round 3
// 253.522 us; speedup vs baseline: 10.7084x; 10.7084x over previous
//
#include <hip/hip_runtime.h>

typedef __attribute__((ext_vector_type(8))) short short8;
typedef _Float16 half8 __attribute__((ext_vector_type(8)));
typedef __attribute__((ext_vector_type(4))) float f32x4;
typedef __attribute__((ext_vector_type(4))) unsigned int uint4v;
typedef __attribute__((ext_vector_type(2))) unsigned int uint2v;

#define B_   8
#define LX_  2048
#define LY_  2048
#define D_   256

__device__ __forceinline__ unsigned short f2bf(float f) {
  unsigned u = __builtin_bit_cast(unsigned, f);
  u += 0x7FFF + ((u >> 16) & 1);          // RNE truncate (inputs are finite)
  return (unsigned short)(u >> 16);
}
__device__ __forceinline__ float bf2f(unsigned short h) {
  unsigned u = ((unsigned)h) << 16;
  return __builtin_bit_cast(float, u);
}

// ---------------- W -> hi/lo bf16 split (65536 elems) ----------------
__global__ __launch_bounds__(256) void wsplit_kernel(
    const float* __restrict__ W, unsigned short* __restrict__ Whi,
    unsigned short* __restrict__ Wlo) {
  int i = blockIdx.x * 256 + threadIdx.x;
  float w = W[i];
  unsigned short hi = f2bf(w);
  Whi[i] = hi;
  Wlo[i] = f2bf(w - bf2f(hi));
}

// ---------------- proj = relu(in @ W^T + b), exact via bf16 hi/lo split
// LDS-tiled GEMM. Grid 512: blocks 0..255 -> X rows, 256..511 -> Y rows.
// Block: 64 rows x 256 cols, K-chunks of 32. Wave w: cols [w*64, w*64+64).
__global__ __launch_bounds__(256, 2) void proj_kernel(
    const float* __restrict__ X, const float* __restrict__ Y,
    const float* __restrict__ bias,
    const unsigned short* __restrict__ Whi, const unsigned short* __restrict__ Wlo,
    _Float16* __restrict__ XP, _Float16* __restrict__ YP) {
  __shared__ unsigned short Ah[64][40], Al[64][40];    // 80B rows: 16B-aligned, 20-bank stride
  __shared__ unsigned short Bh[256][40], Bl[256][40];  // 50 KB total

  int t = threadIdx.x;
  int lane = t & 63, wave = t >> 6;
  int q = lane >> 4, n15 = lane & 15;

  const float* src;
  _Float16* dst;
  int m0;
  if (blockIdx.x < 256) { src = X; dst = XP; m0 = blockIdx.x * 64; }
  else                  { src = Y; dst = YP; m0 = (blockIdx.x - 256) * 64; }

  f32x4 acc[4][4];
  for (int mt = 0; mt < 4; ++mt)
    for (int nt = 0; nt < 4; ++nt) acc[mt][nt] = (f32x4){0.f, 0.f, 0.f, 0.f};

  int arow = t >> 2;          // A staging: 64 rows, 4 threads/row
  int aseg = t & 3;
  int erow = t >> 2, ec = t & 3;  // B staging: 64 e-rows/pass, 4 threads/row

  for (int kc = 0; kc < 8; ++kc) {
    __syncthreads();
    // ---- stage A chunk [64 rows][32 k] fp32 -> hi/lo bf16
    for (int i = 0; i < 2; ++i) {
      int seg = aseg + i * 4;                      // 8 segs of 4 fp32
      f32x4 f = *(const f32x4*)(src + (size_t)(m0 + arow) * D_ + kc * 32 + seg * 4);
      unsigned short h[4], l[4];
      for (int j = 0; j < 4; ++j) {
        h[j] = f2bf(f[j]);
        l[j] = f2bf(f[j] - bf2f(h[j]));
      }
      uint2v vh = {(unsigned)h[0] | ((unsigned)h[1] << 16),
                   (unsigned)h[2] | ((unsigned)h[3] << 16)};
      uint2v vl = {(unsigned)l[0] | ((unsigned)l[1] << 16),
                   (unsigned)l[2] | ((unsigned)l[3] << 16)};
      *(uint2v*)&Ah[arow][seg * 4] = vh;
      *(uint2v*)&Al[arow][seg * 4] = vl;
    }
    // ---- stage B chunk [256 e][32 k] hi+lo (coalesced: 4 lanes x 16B per row)
    for (int pass = 0; pass < 4; ++pass) {
      int e = pass * 64 + erow;
      uint4v vh = *(const uint4v*)(Whi + (size_t)e * D_ + kc * 32 + ec * 8);
      uint4v vl = *(const uint4v*)(Wlo + (size_t)e * D_ + kc * 32 + ec * 8);
      *(uint4v*)&Bh[e][ec * 8] = vh;
      *(uint4v*)&Bl[e][ec * 8] = vl;
    }
    __syncthreads();
    // ---- one k32 MFMA step: 16 ds_read_b128, 48 MFMA
    short8 afh[4], afl[4], bfh[4], bfl[4];
    for (int mt = 0; mt < 4; ++mt) {
      afh[mt] = *(const short8*)&Ah[mt * 16 + n15][q * 8];
      afl[mt] = *(const short8*)&Al[mt * 16 + n15][q * 8];
    }
    for (int nt = 0; nt < 4; ++nt) {
      bfh[nt] = *(const short8*)&Bh[wave * 64 + nt * 16 + n15][q * 8];
      bfl[nt] = *(const short8*)&Bl[wave * 64 + nt * 16 + n15][q * 8];
    }
    for (int mt = 0; mt < 4; ++mt)
      for (int nt = 0; nt < 4; ++nt) {
        acc[mt][nt] = __builtin_amdgcn_mfma_f32_16x16x32_bf16(afh[mt], bfh[nt], acc[mt][nt], 0, 0, 0);
        acc[mt][nt] = __builtin_amdgcn_mfma_f32_16x16x32_bf16(afl[mt], bfh[nt], acc[mt][nt], 0, 0, 0);
        acc[mt][nt] = __builtin_amdgcn_mfma_f32_16x16x32_bf16(afh[mt], bfl[nt], acc[mt][nt], 0, 0, 0);
      }
  }

  // ---- epilogue: bias + relu + fp16 store
  for (int nt = 0; nt < 4; ++nt) {
    int e = wave * 64 + nt * 16 + n15;
    float bv = bias[e];
    for (int mt = 0; mt < 4; ++mt)
      for (int r = 0; r < 4; ++r) {
        float v = acc[mt][nt][r] + bv;
        v = v > 0.f ? v : 0.f;
        dst[(size_t)(m0 + mt * 16 + q * 4 + r) * D_ + e] = (_Float16)v;
      }
  }
}

// ---------------- y fp32 [B][LY][D] -> yT fp16 [B][D][LY] -------------
__global__ __launch_bounds__(256) void transpose_kernel(
    const float* __restrict__ Y, _Float16* __restrict__ YT) {
  __shared__ _Float16 tile[64][72];  // +8 pad, rows 16B-aligned
  int id = blockIdx.x;
  int db = id & 3, nb = (id >> 2) & 31, b = id >> 7;
  int t = threadIdx.x;
  int nl = t >> 2, ds = t & 3;
  const float* src = Y + (size_t)(b * LY_ + nb * 64 + nl) * D_ + db * 64 + ds * 16;
  for (int i = 0; i < 4; ++i) {
    f32x4 f = *(const f32x4*)(src + i * 4);
    for (int j = 0; j < 4; ++j) tile[ds * 16 + i * 4 + j][nl] = (_Float16)f[j];
  }
  __syncthreads();
  int dl = t >> 2, nsub = t & 3;
  uint4v v0 = *(const uint4v*)&tile[dl][nsub * 16];
  uint4v v1 = *(const uint4v*)&tile[dl][nsub * 16 + 8];
  _Float16* dst = YT + (size_t)(b * D_ + db * 64 + dl) * LY_ + nb * 64 + nsub * 16;
  *(uint4v*)(dst) = v0;
  *(uint4v*)(dst + 8) = v1;
}

// ---------------- flash attention over y tiles ------------------------
// grid 256: (b, 64 x-rows). 4 waves x 16 rows. y tiles of 32.
__global__ __launch_bounds__(256) void flash_kernel(
    const _Float16* __restrict__ XP, const _Float16* __restrict__ YP,
    const _Float16* __restrict__ YT, const int* __restrict__ MASK,
    float* __restrict__ OUT) {
  __shared__ _Float16 yp_t[32][264];   // [n][d], +8 pad (row = 528 B, 16B-aligned)
  __shared__ _Float16 yT_t[256][40];   // [d][n], +8 pad (row = 80 B)
  __shared__ _Float16 pbuf[4][16][40]; // per-wave P round-trip
  __shared__ int msk[32];

  int t = threadIdx.x;
  int lane = t & 63, wave = t >> 6;
  int q = lane >> 4, n15 = lane & 15;
  int b = blockIdx.x >> 5, xb = blockIdx.x & 31;
  int row0 = xb * 64 + wave * 16;

  // x_proj A-fragments for this wave's 16 rows (kept in regs all loop)
  half8 a[8];
  const _Float16* xrow = XP + (size_t)(b * LX_ + row0 + n15) * D_ + q * 8;
  for (int kk = 0; kk < 8; ++kk) a[kk] = *(const half8*)(xrow + kk * 32);

  float m_r[4], l_r[4];
  for (int r = 0; r < 4; ++r) { m_r[r] = -1e30f; l_r[r] = 0.f; }
  f32x4 oacc[16];
  for (int dt = 0; dt < 16; ++dt) oacc[dt] = (f32x4){0.f, 0.f, 0.f, 0.f};

  const _Float16* ypb = YP + (size_t)b * LY_ * D_;
  const _Float16* yTb = YT + (size_t)b * D_ * LY_;
  const int* mb = MASK + b * LY_;

  for (int y0 = 0; y0 < LY_; y0 += 32) {
    __syncthreads();  // previous iteration's consumers done
    // stage y_proj tile [32][256] fp16 : 1024 16B chunks
    for (int i = 0; i < 4; ++i) {
      int c = t + i * 256;
      int n = c >> 5, dc = c & 31;
      uint4v v = *(const uint4v*)(ypb + (size_t)(y0 + n) * D_ + dc * 8);
      *(uint4v*)&yp_t[n][dc * 8] = v;
    }
    // stage yT tile [256][32] fp16 : 1024 16B chunks
    for (int i = 0; i < 4; ++i) {
      int c = t + i * 256;
      int d = c >> 2, nc = c & 3;
      uint4v v = *(const uint4v*)(yTb + (size_t)d * LY_ + y0 + nc * 8);
      *(uint4v*)&yT_t[d][nc * 8] = v;
    }
    if (t < 32) msk[t] = mb[y0 + t];
    __syncthreads();

    // ---- QK^T : S[16m x 32n], two 16-col MFMA chains
    f32x4 S0 = {0.f, 0.f, 0.f, 0.f}, S1 = {0.f, 0.f, 0.f, 0.f};
    for (int kk = 0; kk < 8; ++kk) {
      half8 b0 = *(const half8*)&yp_t[n15][kk * 32 + q * 8];
      S0 = __builtin_amdgcn_mfma_f32_16x16x32_f16(a[kk], b0, S0, 0, 0, 0);
    }
    for (int kk = 0; kk < 8; ++kk) {
      half8 b1 = *(const half8*)&yp_t[16 + n15][kk * 32 + q * 8];
      S1 = __builtin_amdgcn_mfma_f32_16x16x32_f16(a[kk], b1, S1, 0, 0, 0);
    }
    int mk0 = msk[n15], mk1 = msk[16 + n15];
    float s0[4], s1[4];
    for (int r = 0; r < 4; ++r) {
      s0[r] = mk0 ? -1e30f : S0[r];
      s1[r] = mk1 ? -1e30f : S1[r];
    }
    // ---- online softmax (rows = q*4+r live in 16-lane quad groups)
    float al[4];
    _Float16 ph0[4], ph1[4];
    bool allone = true;
    for (int r = 0; r < 4; ++r) {
      float tm = fmaxf(s0[r], s1[r]);
      tm = fmaxf(tm, __shfl_xor(tm, 1));
      tm = fmaxf(tm, __shfl_xor(tm, 2));
      tm = fmaxf(tm, __shfl_xor(tm, 4));
      tm = fmaxf(tm, __shfl_xor(tm, 8));
      float mn = fmaxf(m_r[r], tm);
      al[r] = __expf(m_r[r] - mn);
      m_r[r] = mn;
      // round p to fp16 FIRST, then use the rounded value for both l and PV
      ph0[r] = (_Float16)__expf(s0[r] - mn);
      ph1[r] = (_Float16)__expf(s1[r] - mn);
      float rsv = (float)ph0[r] + (float)ph1[r];
      rsv += __shfl_xor(rsv, 1);
      rsv += __shfl_xor(rsv, 2);
      rsv += __shfl_xor(rsv, 4);
      rsv += __shfl_xor(rsv, 8);
      l_r[r] = l_r[r] * al[r] + rsv;
      allone = allone && (al[r] == 1.0f);
    }
    if (__ballot(!allone)) {  // wave-uniform skip when max unchanged
      for (int dt = 0; dt < 16; ++dt)
        for (int r = 0; r < 4; ++r) oacc[dt][r] *= al[r];
    }
    // ---- P: C-layout -> LDS -> A-layout (wave-local, in-order DS pipe)
    for (int r = 0; r < 4; ++r) {
      pbuf[wave][q * 4 + r][n15] = ph0[r];
      pbuf[wave][q * 4 + r][16 + n15] = ph1[r];
    }
    half8 pa = *(const half8*)&pbuf[wave][n15][q * 8];
    // ---- PV: O[16m x 256d] += P[16x32] @ y[32x256]
    for (int dt = 0; dt < 16; ++dt) {
      half8 bb = *(const half8*)&yT_t[dt * 16 + n15][q * 8];
      oacc[dt] = __builtin_amdgcn_mfma_f32_16x16x32_f16(pa, bb, oacc[dt], 0, 0, 0);
    }
  }

  // epilogue: O / l
  float inv[4];
  for (int r = 0; r < 4; ++r) inv[r] = 1.0f / l_r[r];
  float* ob = OUT + (size_t)(b * LX_ + row0) * D_;
  for (int dt = 0; dt < 16; ++dt)
    for (int r = 0; r < 4; ++r)
      ob[(size_t)(q * 4 + r) * D_ + dt * 16 + n15] = oacc[dt][r] * inv[r];
}

extern "C" void kernel_launch(void* const* d_in, const int* in_sizes, int n_in,
                              void* d_out, int out_size, void* d_ws, size_t ws_size,
                              hipStream_t stream) {
  const float* x     = (const float*)d_in[0];  // [8,2048,256]
  const float* y     = (const float*)d_in[1];  // [8,2048,256]
  const int*   ymask = (const int*)  d_in[2];  // [8,2048]
  const float* W     = (const float*)d_in[3];  // [256,256]
  const float* bias  = (const float*)d_in[4];  // [256]
  float* out = (float*)d_out;

  // ws layout (~24.5 MB total)
  char* ws = (char*)d_ws;
  unsigned short* Whi = (unsigned short*)(ws);                    // 128 KB
  unsigned short* Wlo = (unsigned short*)(ws + (131072));         // 128 KB
  _Float16* XP  = (_Float16*)(ws + (262144));                     // 8 MB
  _Float16* YP  = (_Float16*)(ws + (262144 + 8388608));           // 8 MB
  _Float16* YT  = (_Float16*)(ws + (262144 + 2 * 8388608));       // 8 MB

  wsplit_kernel<<<256, 256, 0, stream>>>(W, Whi, Wlo);
  proj_kernel<<<512, 256, 0, stream>>>(x, y, bias, Whi, Wlo, XP, YP);
  transpose_kernel<<<1024, 256, 0, stream>>>(y, YT);
  flash_kernel<<<256, 256, 0, stream>>>(XP, YP, YT, ymask, out);
}

// Round 4
// 208.229 us; speedup vs baseline: 13.0377x; 1.2175x over previous
//
#include <hip/hip_runtime.h>

typedef __attribute__((ext_vector_type(8))) short short8;
typedef _Float16 half8 __attribute__((ext_vector_type(8)));
typedef __attribute__((ext_vector_type(4))) float f32x4;
typedef __attribute__((ext_vector_type(4))) unsigned int uint4v;
typedef __attribute__((ext_vector_type(2))) unsigned int uint2v;

#define B_   8
#define LX_  2048
#define LY_  2048
#define D_   256
#define NROW (B_ * LX_)   // 16384

__device__ __forceinline__ unsigned short f2bf(float f) {
  unsigned u = __builtin_bit_cast(unsigned, f);
  u += 0x7FFF + ((u >> 16) & 1);          // RNE truncate (inputs are finite)
  return (unsigned short)(u >> 16);
}
__device__ __forceinline__ float bf2f(unsigned short h) {
  unsigned u = ((unsigned)h) << 16;
  return __builtin_bit_cast(float, u);
}

// ---------------- W -> hi/lo bf16 split (65536 elems) ----------------
__global__ __launch_bounds__(256) void wsplit_kernel(
    const float* __restrict__ W, unsigned short* __restrict__ Whi,
    unsigned short* __restrict__ Wlo) {
  int i = blockIdx.x * 256 + threadIdx.x;
  float w = W[i];
  unsigned short hi = f2bf(w);
  Whi[i] = hi;
  Wlo[i] = f2bf(w - bf2f(hi));
}

// ---------------- proj = relu(in @ W^T + b), exact via bf16 hi/lo split
// LDS-tiled GEMM. Grid 512: blocks 0..255 -> X rows, 256..511 -> Y rows.
// Block: 64 rows x 256 cols, K-chunks of 32. Wave w: cols [w*64, w*64+64).
__global__ __launch_bounds__(256, 2) void proj_kernel(
    const float* __restrict__ X, const float* __restrict__ Y,
    const float* __restrict__ bias,
    const unsigned short* __restrict__ Whi, const unsigned short* __restrict__ Wlo,
    _Float16* __restrict__ XP, _Float16* __restrict__ YP) {
  __shared__ unsigned short Ah[64][40], Al[64][40];    // 80B rows: 16B-aligned, 20-bank stride
  __shared__ unsigned short Bh[256][40], Bl[256][40];  // 50 KB total

  int t = threadIdx.x;
  int lane = t & 63, wave = t >> 6;
  int q = lane >> 4, n15 = lane & 15;

  const float* src;
  _Float16* dst;
  int m0;
  if (blockIdx.x < 256) { src = X; dst = XP; m0 = blockIdx.x * 64; }
  else                  { src = Y; dst = YP; m0 = (blockIdx.x - 256) * 64; }

  f32x4 acc[4][4];
  for (int mt = 0; mt < 4; ++mt)
    for (int nt = 0; nt < 4; ++nt) acc[mt][nt] = (f32x4){0.f, 0.f, 0.f, 0.f};

  int arow = t >> 2;          // A staging: 64 rows, 4 threads/row
  int aseg = t & 3;
  int erow = t >> 2, ec = t & 3;  // B staging: 64 e-rows/pass, 4 threads/row

  for (int kc = 0; kc < 8; ++kc) {
    __syncthreads();
    // ---- stage A chunk [64 rows][32 k] fp32 -> hi/lo bf16
    for (int i = 0; i < 2; ++i) {
      int seg = aseg + i * 4;                      // 8 segs of 4 fp32
      f32x4 f = *(const f32x4*)(src + (size_t)(m0 + arow) * D_ + kc * 32 + seg * 4);
      unsigned short h[4], l[4];
      for (int j = 0; j < 4; ++j) {
        h[j] = f2bf(f[j]);
        l[j] = f2bf(f[j] - bf2f(h[j]));
      }
      uint2v vh = {(unsigned)h[0] | ((unsigned)h[1] << 16),
                   (unsigned)h[2] | ((unsigned)h[3] << 16)};
      uint2v vl = {(unsigned)l[0] | ((unsigned)l[1] << 16),
                   (unsigned)l[2] | ((unsigned)l[3] << 16)};
      *(uint2v*)&Ah[arow][seg * 4] = vh;
      *(uint2v*)&Al[arow][seg * 4] = vl;
    }
    // ---- stage B chunk [256 e][32 k] hi+lo (coalesced: 4 lanes x 16B per row)
    for (int pass = 0; pass < 4; ++pass) {
      int e = pass * 64 + erow;
      uint4v vh = *(const uint4v*)(Whi + (size_t)e * D_ + kc * 32 + ec * 8);
      uint4v vl = *(const uint4v*)(Wlo + (size_t)e * D_ + kc * 32 + ec * 8);
      *(uint4v*)&Bh[e][ec * 8] = vh;
      *(uint4v*)&Bl[e][ec * 8] = vl;
    }
    __syncthreads();
    // ---- one k32 MFMA step: 16 ds_read_b128, 48 MFMA
    short8 afh[4], afl[4], bfh[4], bfl[4];
    for (int mt = 0; mt < 4; ++mt) {
      afh[mt] = *(const short8*)&Ah[mt * 16 + n15][q * 8];
      afl[mt] = *(const short8*)&Al[mt * 16 + n15][q * 8];
    }
    for (int nt = 0; nt < 4; ++nt) {
      bfh[nt] = *(const short8*)&Bh[wave * 64 + nt * 16 + n15][q * 8];
      bfl[nt] = *(const short8*)&Bl[wave * 64 + nt * 16 + n15][q * 8];
    }
    for (int mt = 0; mt < 4; ++mt)
      for (int nt = 0; nt < 4; ++nt) {
        acc[mt][nt] = __builtin_amdgcn_mfma_f32_16x16x32_bf16(afh[mt], bfh[nt], acc[mt][nt], 0, 0, 0);
        acc[mt][nt] = __builtin_amdgcn_mfma_f32_16x16x32_bf16(afl[mt], bfh[nt], acc[mt][nt], 0, 0, 0);
        acc[mt][nt] = __builtin_amdgcn_mfma_f32_16x16x32_bf16(afh[mt], bfl[nt], acc[mt][nt], 0, 0, 0);
      }
  }

  // ---- epilogue: bias + relu + fp16 store
  for (int nt = 0; nt < 4; ++nt) {
    int e = wave * 64 + nt * 16 + n15;
    float bv = bias[e];
    for (int mt = 0; mt < 4; ++mt)
      for (int r = 0; r < 4; ++r) {
        float v = acc[mt][nt][r] + bv;
        v = v > 0.f ? v : 0.f;
        dst[(size_t)(m0 + mt * 16 + q * 4 + r) * D_ + e] = (_Float16)v;
      }
  }
}

// ---------------- y fp32 [B][LY][D] -> yT fp16 [B][D][LY] -------------
__global__ __launch_bounds__(256) void transpose_kernel(
    const float* __restrict__ Y, _Float16* __restrict__ YT) {
  __shared__ _Float16 tile[64][72];  // +8 pad, rows 16B-aligned
  int id = blockIdx.x;
  int db = id & 3, nb = (id >> 2) & 31, b = id >> 7;
  int t = threadIdx.x;
  int nl = t >> 2, ds = t & 3;
  const float* src = Y + (size_t)(b * LY_ + nb * 64 + nl) * D_ + db * 64 + ds * 16;
  for (int i = 0; i < 4; ++i) {
    f32x4 f = *(const f32x4*)(src + i * 4);
    for (int j = 0; j < 4; ++j) tile[ds * 16 + i * 4 + j][nl] = (_Float16)f[j];
  }
  __syncthreads();
  int dl = t >> 2, nsub = t & 3;
  uint4v v0 = *(const uint4v*)&tile[dl][nsub * 16];
  uint4v v1 = *(const uint4v*)&tile[dl][nsub * 16 + 8];
  _Float16* dst = YT + (size_t)(b * D_ + db * 64 + dl) * LY_ + nb * 64 + nsub * 16;
  *(uint4v*)(dst) = v0;
  *(uint4v*)(dst + 8) = v1;
}

// ---------------- flash attention, split-LY partials -----------------
// grid 512: (b, 64 x-rows, LY-half). 4 waves x 16 rows. y tiles of 32.
// Writes fp16 O-numerator partial + fp32 (m,l) per row.
__global__ __launch_bounds__(256) void flash_kernel(
    const _Float16* __restrict__ XP, const _Float16* __restrict__ YP,
    const _Float16* __restrict__ YT, const int* __restrict__ MASK,
    _Float16* __restrict__ PO, float* __restrict__ Pm, float* __restrict__ Pl) {
  __shared__ _Float16 yp_t[32][264];   // [n][d], +8 pad (row = 528 B, 16B-aligned)
  __shared__ _Float16 yT_t[256][40];   // [d][n], +8 pad (row = 80 B)
  __shared__ _Float16 pbuf[4][16][40]; // per-wave P round-trip
  __shared__ int msk[32];

  int t = threadIdx.x;
  int lane = t & 63, wave = t >> 6;
  int q = lane >> 4, n15 = lane & 15;
  int half = blockIdx.x & 1;
  int xb = (blockIdx.x >> 1) & 31;
  int b = blockIdx.x >> 6;
  int row0 = xb * 64 + wave * 16;
  int y_start = half * (LY_ / 2);

  // x_proj A-fragments for this wave's 16 rows (kept in regs all loop)
  half8 a[8];
  const _Float16* xrow = XP + (size_t)(b * LX_ + row0 + n15) * D_ + q * 8;
  for (int kk = 0; kk < 8; ++kk) a[kk] = *(const half8*)(xrow + kk * 32);

  float m_r[4], l_r[4];
  for (int r = 0; r < 4; ++r) { m_r[r] = -1e30f; l_r[r] = 0.f; }
  f32x4 oacc[16];
  for (int dt = 0; dt < 16; ++dt) oacc[dt] = (f32x4){0.f, 0.f, 0.f, 0.f};

  const _Float16* ypb = YP + (size_t)b * LY_ * D_;
  const _Float16* yTb = YT + (size_t)b * D_ * LY_;
  const int* mb = MASK + b * LY_;

  for (int y0 = y_start; y0 < y_start + LY_ / 2; y0 += 32) {
    __syncthreads();  // previous iteration's consumers done
    // stage y_proj tile [32][256] fp16 : 1024 16B chunks
    for (int i = 0; i < 4; ++i) {
      int c = t + i * 256;
      int n = c >> 5, dc = c & 31;
      uint4v v = *(const uint4v*)(ypb + (size_t)(y0 + n) * D_ + dc * 8);
      *(uint4v*)&yp_t[n][dc * 8] = v;
    }
    // stage yT tile [256][32] fp16 : 1024 16B chunks
    for (int i = 0; i < 4; ++i) {
      int c = t + i * 256;
      int d = c >> 2, nc = c & 3;
      uint4v v = *(const uint4v*)(yTb + (size_t)d * LY_ + y0 + nc * 8);
      *(uint4v*)&yT_t[d][nc * 8] = v;
    }
    if (t < 32) msk[t] = mb[y0 + t];
    __syncthreads();

    // ---- QK^T : S[16m x 32n], two 16-col MFMA chains
    f32x4 S0 = {0.f, 0.f, 0.f, 0.f}, S1 = {0.f, 0.f, 0.f, 0.f};
    for (int kk = 0; kk < 8; ++kk) {
      half8 b0 = *(const half8*)&yp_t[n15][kk * 32 + q * 8];
      S0 = __builtin_amdgcn_mfma_f32_16x16x32_f16(a[kk], b0, S0, 0, 0, 0);
    }
    for (int kk = 0; kk < 8; ++kk) {
      half8 b1 = *(const half8*)&yp_t[16 + n15][kk * 32 + q * 8];
      S1 = __builtin_amdgcn_mfma_f32_16x16x32_f16(a[kk], b1, S1, 0, 0, 0);
    }
    int mk0 = msk[n15], mk1 = msk[16 + n15];
    float s0[4], s1[4];
    for (int r = 0; r < 4; ++r) {
      s0[r] = mk0 ? -1e30f : S0[r];
      s1[r] = mk1 ? -1e30f : S1[r];
    }
    // ---- online softmax (rows = q*4+r live in 16-lane quad groups)
    float al[4];
    _Float16 ph0[4], ph1[4];
    bool allone = true;
    for (int r = 0; r < 4; ++r) {
      float tm = fmaxf(s0[r], s1[r]);
      tm = fmaxf(tm, __shfl_xor(tm, 1));
      tm = fmaxf(tm, __shfl_xor(tm, 2));
      tm = fmaxf(tm, __shfl_xor(tm, 4));
      tm = fmaxf(tm, __shfl_xor(tm, 8));
      float mn = fmaxf(m_r[r], tm);
      al[r] = __expf(m_r[r] - mn);
      m_r[r] = mn;
      // round p to fp16 FIRST, then use the rounded value for both l and PV
      ph0[r] = (_Float16)__expf(s0[r] - mn);
      ph1[r] = (_Float16)__expf(s1[r] - mn);
      float rsv = (float)ph0[r] + (float)ph1[r];
      rsv += __shfl_xor(rsv, 1);
      rsv += __shfl_xor(rsv, 2);
      rsv += __shfl_xor(rsv, 4);
      rsv += __shfl_xor(rsv, 8);
      l_r[r] = l_r[r] * al[r] + rsv;
      allone = allone && (al[r] == 1.0f);
    }
    if (__ballot(!allone)) {  // wave-uniform skip when max unchanged
      for (int dt = 0; dt < 16; ++dt)
        for (int r = 0; r < 4; ++r) oacc[dt][r] *= al[r];
    }
    // ---- P: C-layout -> LDS -> A-layout (wave-local, in-order DS pipe)
    for (int r = 0; r < 4; ++r) {
      pbuf[wave][q * 4 + r][n15] = ph0[r];
      pbuf[wave][q * 4 + r][16 + n15] = ph1[r];
    }
    half8 pa = *(const half8*)&pbuf[wave][n15][q * 8];
    // ---- PV: O[16m x 256d] += P[16x32] @ y[32x256]
    for (int dt = 0; dt < 16; ++dt) {
      half8 bb = *(const half8*)&yT_t[dt * 16 + n15][q * 8];
      oacc[dt] = __builtin_amdgcn_mfma_f32_16x16x32_f16(pa, bb, oacc[dt], 0, 0, 0);
    }
  }

  // epilogue: store unnormalized numerator (fp16) + per-row m,l (fp32)
  size_t prow = (size_t)(half * B_ + b) * LX_ + row0;
  _Float16* po = PO + prow * D_;
  for (int dt = 0; dt < 16; ++dt)
    for (int r = 0; r < 4; ++r)
      po[(size_t)(q * 4 + r) * D_ + dt * 16 + n15] = (_Float16)oacc[dt][r];
  if (n15 == 0) {
    for (int r = 0; r < 4; ++r) {
      Pm[prow + q * 4 + r] = m_r[r];
      Pl[prow + q * 4 + r] = l_r[r];
    }
  }
}

// ---------------- merge the two LY-half partials ----------------------
// grid 2048 x 256: one thread per 8 output elements.
__global__ __launch_bounds__(256) void merge_kernel(
    const _Float16* __restrict__ PO, const float* __restrict__ Pm,
    const float* __restrict__ Pl, float* __restrict__ OUT) {
  int c = blockIdx.x * 256 + threadIdx.x;  // [0, 524288)
  int row = c >> 5, seg = c & 31;
  float m0 = Pm[row], m1 = Pm[NROW + row];
  float l0 = Pl[row], l1 = Pl[NROW + row];
  float m = fmaxf(m0, m1);
  float w0 = __expf(m0 - m), w1 = __expf(m1 - m);
  float inv = 1.0f / (l0 * w0 + l1 * w1);
  const _Float16* p0 = PO + (size_t)row * D_ + seg * 8;
  const _Float16* p1 = p0 + (size_t)NROW * D_;
  half8 a = *(const half8*)p0;
  half8 bsec = *(const half8*)p1;
  float* o = OUT + (size_t)row * D_ + seg * 8;
  f32x4 o0, o1;
  for (int j = 0; j < 4; ++j) o0[j] = ((float)a[j] * w0 + (float)bsec[j] * w1) * inv;
  for (int j = 0; j < 4; ++j) o1[j] = ((float)a[4 + j] * w0 + (float)bsec[4 + j] * w1) * inv;
  *(f32x4*)o = o0;
  *(f32x4*)(o + 4) = o1;
}

extern "C" void kernel_launch(void* const* d_in, const int* in_sizes, int n_in,
                              void* d_out, int out_size, void* d_ws, size_t ws_size,
                              hipStream_t stream) {
  const float* x     = (const float*)d_in[0];  // [8,2048,256]
  const float* y     = (const float*)d_in[1];  // [8,2048,256]
  const int*   ymask = (const int*)  d_in[2];  // [8,2048]
  const float* W     = (const float*)d_in[3];  // [256,256]
  const float* bias  = (const float*)d_in[4];  // [256]
  float* out = (float*)d_out;

  // ws layout (~42.5 MB total)
  char* ws = (char*)d_ws;
  unsigned short* Whi = (unsigned short*)(ws);                    // 128 KB
  unsigned short* Wlo = (unsigned short*)(ws + 131072);           // 128 KB
  _Float16* XP  = (_Float16*)(ws + 262144);                       // 8 MB
  _Float16* YP  = (_Float16*)(ws + 262144 + 8388608);             // 8 MB
  _Float16* YT  = (_Float16*)(ws + 262144 + 2 * 8388608);         // 8 MB
  _Float16* PO  = (_Float16*)(ws + 262144 + 3 * 8388608);         // 16 MB (2 halves)
  float*    Pm  = (float*)   (ws + 262144 + 3 * 8388608 + 16777216);   // 128 KB
  float*    Pl  = (float*)   (ws + 262144 + 3 * 8388608 + 16777216 + 131072);

  wsplit_kernel<<<256, 256, 0, stream>>>(W, Whi, Wlo);
  proj_kernel<<<512, 256, 0, stream>>>(x, y, bias, Whi, Wlo, XP, YP);
  transpose_kernel<<<1024, 256, 0, stream>>>(y, YT);
  flash_kernel<<<512, 256, 0, stream>>>(XP, YP, YT, ymask, PO, Pm, Pl);
  merge_kernel<<<2048, 256, 0, stream>>>(PO, Pm, Pl, out);
}